// Round 5
// baseline (186.615 us; speedup 1.0000x reference)
//
#include <hip/hip_runtime.h>
#include <hip/hip_bf16.h>
#include <math.h>

typedef __bf16 bf16;
typedef __bf16 bf16x8 __attribute__((ext_vector_type(8)));
typedef float  f32x4  __attribute__((ext_vector_type(4)));

#define MFMA16(a, b, c) __builtin_amdgcn_mfma_f32_16x16x32_bf16((a), (b), (c), 0, 0, 0)

constexpr int B_ = 8, C_ = 80, T_ = 2048, D_ = 256;
constexpr int NS = 4;                       // j-splits (flash-decode style)
constexpr float SCALE_INV = 1.0f / 16.0f;   // 1/sqrt(256)

// ---------------------------------------------------------------------------
// Kernel 1: projection. K = xt @ Wk^T + bk, Q = xt @ Wq^T + bq (bf16 out),
// plus bf16 conversion of x (kept in [B][C][T] layout = V^T for the PV step).
// Bias folded in by padding C 80->96 with xt[:,80]=1, W[:,80]=bias.
// ---------------------------------------------------------------------------
__global__ __launch_bounds__(256) void proj_kernel(
    const float* __restrict__ x,   // [B][C][T]
    const float* __restrict__ Wk,  // [D][C]
    const float* __restrict__ bk,  // [D]
    const float* __restrict__ Wq,  // [D][C]
    const float* __restrict__ bq,  // [D]
    bf16* __restrict__ Kb,         // [B][T][D]
    bf16* __restrict__ Qb,         // [B][T][D]
    bf16* __restrict__ xbf)        // [B][C][T]
{
  const int t0   = blockIdx.x * 32;
  const int b    = blockIdx.y;
  const int tid  = threadIdx.x;
  const int w    = tid >> 6;
  const int lane = tid & 63;
  const int h    = lane >> 4;   // 0..3
  const int lr   = lane & 15;   // 0..15

  const float* xb = x + (size_t)b * C_ * T_;

  // bf16-convert this block's x slice
  {
    bf16* ob = xbf + (size_t)b * C_ * T_;
    #pragma unroll
    for (int q = 0; q < 10; ++q) {
      int idx = q * 256 + tid;
      int c = idx >> 5, tt = idx & 31;
      ob[c * T_ + t0 + tt] = (bf16)xb[c * T_ + t0 + tt];
    }
  }

  // A-fragments: xt rows t0..t0+31, c padded to 96
  bf16x8 afrag[2][3];
  #pragma unroll
  for (int ib = 0; ib < 2; ++ib) {
    int t = t0 + ib * 16 + lr;
    #pragma unroll
    for (int ks = 0; ks < 3; ++ks) {
      bf16x8 v;
      #pragma unroll
      for (int e = 0; e < 8; ++e) {
        int c = ks * 32 + h * 8 + e;
        float val;
        if (c < 80)       val = xb[c * T_ + t];
        else if (c == 80) val = 1.0f;
        else              val = 0.0f;
        v[e] = (bf16)val;
      }
      afrag[ib][ks] = v;
    }
  }

  const int nb0 = w * 4;
  #pragma unroll
  for (int mat = 0; mat < 2; ++mat) {
    const float* W    = mat ? Wq : Wk;
    const float* bias = mat ? bq : bk;
    bf16* outp        = mat ? Qb : Kb;

    f32x4 acc[2][4];
    #pragma unroll
    for (int ib = 0; ib < 2; ++ib)
      #pragma unroll
      for (int nb = 0; nb < 4; ++nb)
        acc[ib][nb] = f32x4{0.f, 0.f, 0.f, 0.f};

    #pragma unroll
    for (int nb = 0; nb < 4; ++nb) {
      int d = (nb0 + nb) * 16 + lr;
      #pragma unroll
      for (int ks = 0; ks < 3; ++ks) {
        bf16x8 bv;
        #pragma unroll
        for (int e = 0; e < 8; ++e) {
          int c = ks * 32 + h * 8 + e;
          float val;
          if (c < 80)       val = W[d * C_ + c];
          else if (c == 80) val = bias[d];
          else              val = 0.0f;
          bv[e] = (bf16)val;
        }
        #pragma unroll
        for (int ib = 0; ib < 2; ++ib)
          acc[ib][nb] = MFMA16(afrag[ib][ks], bv, acc[ib][nb]);
      }
    }

    #pragma unroll
    for (int ib = 0; ib < 2; ++ib)
      #pragma unroll
      for (int nb = 0; nb < 4; ++nb) {
        int d = (nb0 + nb) * 16 + lr;
        #pragma unroll
        for (int r = 0; r < 4; ++r) {
          int t = t0 + ib * 16 + h * 4 + r;
          outp[(size_t)(b * T_ + t) * D_ + d] = (bf16)acc[ib][nb][r];
        }
      }
  }
}

// ---------------------------------------------------------------------------
// Kernel 2: flash attention, barrier-free. Waves are fully independent:
// Q and V B-fragments stream straight from the XCD-local L2 (batch->XCD
// pinning keeps the 2.3MB/batch working set resident); the only LDS use is
// the tiny per-wave P round-trip (no cross-wave sharing, no __syncthreads).
// Grid flat = b + 8*(i_tile + 32*s) pins batch b to XCD b.
// ---------------------------------------------------------------------------
__global__ __launch_bounds__(256, 4) void attn_kernel(
    const bf16* __restrict__ Kb,   // [B][T][D]
    const bf16* __restrict__ Qb,   // [B][T][D]
    const bf16* __restrict__ xbf,  // [B][C][T]
    float* __restrict__ Opart,     // [NS][B][C][T]
    float* __restrict__ mpart,     // [NS][B][T]
    float* __restrict__ lpart)     // [NS][B][T]
{
  constexpr int BM = 64, BN = 64, NT = T_ / BN;  // NT = 32
  constexpr int JT_PER = NT / NS;                // 8
  __shared__ bf16 plds[4][16 * BN];    // per-wave P buffer, 8 KB total

  const int flat = blockIdx.x;
  const int b    = flat & 7;           // batch -> XCD (round-robin heuristic)
  const int rem  = flat >> 3;
  const int i0   = (rem & 31) * BM;
  const int s    = rem >> 5;

  const int tid  = threadIdx.x;
  const int w    = tid >> 6;
  const int lane = tid & 63;
  const int h    = lane >> 4;
  const int lr   = lane & 15;

  const bf16* Kbase = Kb + (size_t)(b * T_) * D_;
  const bf16* Qbase = Qb + (size_t)(b * T_) * D_;

  // K A-frags for this wave's 16 rows: K[i0+16w+lr][h*8 + ks*32 + e]
  bf16x8 kfrag[8];
  {
    const bf16* kp = Kbase + (size_t)(i0 + w * 16 + lr) * D_ + h * 8;
    #pragma unroll
    for (int ks = 0; ks < 8; ++ks)
      kfrag[ks] = *reinterpret_cast<const bf16x8*>(kp + ks * 32);
  }

  f32x4 oacc[5];
  #pragma unroll
  for (int nb = 0; nb < 5; ++nb) oacc[nb] = f32x4{0.f, 0.f, 0.f, 0.f};
  float m_run[4], l_run[4];
  #pragma unroll
  for (int r = 0; r < 4; ++r) { m_run[r] = -INFINITY; l_run[r] = 0.f; }

  const int jt0 = s * JT_PER, jt_end = jt0 + JT_PER;

  for (int jt = jt0; jt < jt_end; ++jt) {
    // --- S = K Q^T (this wave: 16 i x 64 j); Q B-frags straight from L2.
    //     B-frag: Q[jt*64 + jb*16 + lr][h*8 + ks*32 + e]  (same math the
    //     LDS path reconstructed; 16 rows x 64B per instr, coalesced). ---
    const bf16* qp = Qbase + (size_t)(jt * BN + lr) * D_ + h * 8;
    f32x4 sacc[4];
    #pragma unroll
    for (int jb = 0; jb < 4; ++jb) sacc[jb] = f32x4{0.f, 0.f, 0.f, 0.f};
    __builtin_amdgcn_s_setprio(1);
    #pragma unroll
    for (int jb = 0; jb < 4; ++jb) {
      #pragma unroll
      for (int ks = 0; ks < 8; ++ks) {
        bf16x8 qf = *reinterpret_cast<const bf16x8*>(
            qp + (size_t)(jb * 16) * D_ + ks * 32);
        sacc[jb] = MFMA16(kfrag[ks], qf, sacc[jb]);
      }
    }
    __builtin_amdgcn_s_setprio(0);

    // --- online softmax over this split's j ---
    #pragma unroll
    for (int jb = 0; jb < 4; ++jb)
      #pragma unroll
      for (int r = 0; r < 4; ++r) sacc[jb][r] *= SCALE_INV;

    float p[4][4];
    float alpha[4];
    #pragma unroll
    for (int r = 0; r < 4; ++r) {
      float mx = fmaxf(fmaxf(sacc[0][r], sacc[1][r]), fmaxf(sacc[2][r], sacc[3][r]));
      mx = fmaxf(mx, __shfl_xor(mx, 1));
      mx = fmaxf(mx, __shfl_xor(mx, 2));
      mx = fmaxf(mx, __shfl_xor(mx, 4));
      mx = fmaxf(mx, __shfl_xor(mx, 8));
      float mnew = fmaxf(m_run[r], mx);
      alpha[r]  = __expf(m_run[r] - mnew);
      m_run[r]  = mnew;
      float rs = 0.f;
      #pragma unroll
      for (int jb = 0; jb < 4; ++jb) {
        p[jb][r] = __expf(sacc[jb][r] - mnew);
        rs += p[jb][r];
      }
      rs += __shfl_xor(rs, 1);
      rs += __shfl_xor(rs, 2);
      rs += __shfl_xor(rs, 4);
      rs += __shfl_xor(rs, 8);
      l_run[r] = l_run[r] * alpha[r] + rs;
    }

    #pragma unroll
    for (int nb = 0; nb < 5; ++nb)
      #pragma unroll
      for (int r = 0; r < 4; ++r) oacc[nb][r] *= alpha[r];

    // --- P -> per-wave LDS (bf16, swizzled); same-wave round-trip, no sync ---
    #pragma unroll
    for (int jb = 0; jb < 4; ++jb)
      #pragma unroll
      for (int r = 0; r < 4; ++r) {
        int row = h * 4 + r;
        int col = lr + jb * 16;
        plds[w][row * 64 + (((col >> 3) ^ (row & 7)) << 3) + (col & 7)] =
            (bf16)p[jb][r];
      }

    // --- read P as A-frags, V frags from L2, PV MFMA ---
    bf16x8 pa[2];
    #pragma unroll
    for (int ks = 0; ks < 2; ++ks) {
      pa[ks] = *reinterpret_cast<const bf16x8*>(
          &plds[w][lr * 64 + (((h + 4 * ks) ^ (lr & 7)) << 3)]);
    }
    const bf16* vbase = xbf + (size_t)b * C_ * T_ + jt * BN;
    __builtin_amdgcn_s_setprio(1);
    #pragma unroll
    for (int nb = 0; nb < 5; ++nb) {
      const int c = lr + nb * 16;
      #pragma unroll
      for (int ks = 0; ks < 2; ++ks) {
        bf16x8 vf = *reinterpret_cast<const bf16x8*>(
            &vbase[(size_t)c * T_ + h * 8 + ks * 32]);
        oacc[nb] = MFMA16(pa[ks], vf, oacc[nb]);
      }
    }
    __builtin_amdgcn_s_setprio(0);
  }

  // --- epilogue: unnormalized partials ---
  float* ob = Opart + (size_t)(s * B_ + b) * C_ * T_;
  #pragma unroll
  for (int nb = 0; nb < 5; ++nb) {
    const int c = lr + nb * 16;
    #pragma unroll
    for (int r = 0; r < 4; ++r) {
      const int i = i0 + w * 16 + h * 4 + r;
      ob[(size_t)c * T_ + i] = oacc[nb][r];
    }
  }
  if (lr == 0) {
    #pragma unroll
    for (int r = 0; r < 4; ++r) {
      const int i = i0 + w * 16 + h * 4 + r;
      mpart[(size_t)(s * B_ + b) * T_ + i] = m_run[r];
      lpart[(size_t)(s * B_ + b) * T_ + i] = l_run[r];
    }
  }
}

// ---------------------------------------------------------------------------
// Kernel 3: merge splits. out[b][c][t] = sum_s O_s e^{m_s-m*} / sum_s l_s e^{m_s-m*}
// ---------------------------------------------------------------------------
__global__ __launch_bounds__(256) void merge_kernel(
    const float* __restrict__ Opart,  // [NS][B][C][T]
    const float* __restrict__ mpart,  // [NS][B][T]
    const float* __restrict__ lpart,  // [NS][B][T]
    float* __restrict__ out)          // [B][C][T]
{
  const int b    = blockIdx.y;
  const int tid  = threadIdx.x;
  const int w    = tid >> 6;
  const int lane = tid & 63;
  const int t    = blockIdx.x * 64 + lane;

  float m[NS];
  float mmax = -INFINITY;
  #pragma unroll
  for (int s2 = 0; s2 < NS; ++s2) {
    m[s2] = mpart[(size_t)(s2 * B_ + b) * T_ + t];
    mmax = fmaxf(mmax, m[s2]);
  }
  float e[NS];
  float lsum = 0.f;
  #pragma unroll
  for (int s2 = 0; s2 < NS; ++s2) {
    e[s2] = __expf(m[s2] - mmax);
    lsum += e[s2] * lpart[(size_t)(s2 * B_ + b) * T_ + t];
  }
  const float inv = 1.0f / lsum;

  const int c0 = w * 20;
  for (int c = c0; c < c0 + 20; ++c) {
    float acc = 0.f;
    #pragma unroll
    for (int s2 = 0; s2 < NS; ++s2)
      acc += Opart[((size_t)(s2 * B_ + b) * C_ + c) * T_ + t] * e[s2];
    out[((size_t)b * C_ + c) * T_ + t] = acc * inv;
  }
}

// ---------------------------------------------------------------------------
extern "C" void kernel_launch(void* const* d_in, const int* in_sizes, int n_in,
                              void* d_out, int out_size, void* d_ws, size_t ws_size,
                              hipStream_t stream) {
  (void)in_sizes; (void)n_in; (void)out_size; (void)ws_size;
  const float* x  = (const float*)d_in[0];
  const float* Wk = (const float*)d_in[1];
  const float* bk = (const float*)d_in[2];
  const float* Wq = (const float*)d_in[3];
  const float* bq = (const float*)d_in[4];
  float* out = (float*)d_out;

  char* ws = (char*)d_ws;
  const size_t MB = 1024 * 1024;
  bf16*  Kb    = (bf16*)(ws);                 // 8 MB
  bf16*  Qb    = (bf16*)(ws + 8 * MB);        // 8 MB
  bf16*  xbf   = (bf16*)(ws + 16 * MB);       // 2.625 MB
  float* Opart = (float*)(ws + 19 * MB);      // NS*8*80*2048*4 = 20.97 MB
  float* mpart = (float*)(ws + 41 * MB);      // 256 KB
  float* lpart = (float*)(ws + 42 * MB);      // 256 KB

  dim3 blk(256);
  dim3 g1(T_ / 32, B_);
  proj_kernel<<<g1, blk, 0, stream>>>(x, Wk, bk, Wq, bq, Kb, Qb, xbf);
  attn_kernel<<<dim3(T_ / 64 * NS * B_), blk, 0, stream>>>(Kb, Qb, xbf, Opart, mpart, lpart);
  dim3 g3(T_ / 64, B_);
  merge_kernel<<<g3, blk, 0, stream>>>(Opart, mpart, lpart, out);
}

// Round 6
// 68.203 us; speedup vs baseline: 2.7362x; 2.7362x over previous
//
#include <hip/hip_runtime.h>
#include <hip/hip_bf16.h>
#include <math.h>

typedef __bf16 bf16;
typedef __bf16 bf16x8 __attribute__((ext_vector_type(8)));
typedef float  f32x4  __attribute__((ext_vector_type(4)));
typedef float  f32x16 __attribute__((ext_vector_type(16)));
typedef uint32_t u32x4 __attribute__((ext_vector_type(4)));

#define MFMA16(a, b, c) __builtin_amdgcn_mfma_f32_16x16x32_bf16((a), (b), (c), 0, 0, 0)
#define MFMA32(a, b, c) __builtin_amdgcn_mfma_f32_32x32x16_bf16((a), (b), (c), 0, 0, 0)

typedef const uint32_t __attribute__((address_space(1)))* gq_t;
typedef uint32_t __attribute__((address_space(3)))* lq_t;

constexpr int B_ = 8, C_ = 80, T_ = 2048, D_ = 256;
constexpr int NS = 4;                       // j-splits
constexpr float SCALE_INV = 1.0f / 16.0f;   // 1/sqrt(256)

static __device__ inline uint32_t pkbf(float lo, float hi) {
  bf16 l = (bf16)lo, h = (bf16)hi;
  uint16_t lb = __builtin_bit_cast(uint16_t, l), hb = __builtin_bit_cast(uint16_t, h);
  return (uint32_t)lb | ((uint32_t)hb << 16);
}

// ---------------------------------------------------------------------------
// Kernel 1: projection (unchanged). K/Q = xt@W^T + b (bf16), x -> bf16 copy.
// ---------------------------------------------------------------------------
__global__ __launch_bounds__(256) void proj_kernel(
    const float* __restrict__ x,   // [B][C][T]
    const float* __restrict__ Wk,  // [D][C]
    const float* __restrict__ bk,  // [D]
    const float* __restrict__ Wq,  // [D][C]
    const float* __restrict__ bq,  // [D]
    bf16* __restrict__ Kb,         // [B][T][D]
    bf16* __restrict__ Qb,         // [B][T][D]
    bf16* __restrict__ xbf)        // [B][C][T]
{
  const int t0   = blockIdx.x * 32;
  const int b    = blockIdx.y;
  const int tid  = threadIdx.x;
  const int w    = tid >> 6;
  const int lane = tid & 63;
  const int h    = lane >> 4;
  const int lr   = lane & 15;

  const float* xb = x + (size_t)b * C_ * T_;

  {
    bf16* ob = xbf + (size_t)b * C_ * T_;
    #pragma unroll
    for (int q = 0; q < 10; ++q) {
      int idx = q * 256 + tid;
      int c = idx >> 5, tt = idx & 31;
      ob[c * T_ + t0 + tt] = (bf16)xb[c * T_ + t0 + tt];
    }
  }

  bf16x8 afrag[2][3];
  #pragma unroll
  for (int ib = 0; ib < 2; ++ib) {
    int t = t0 + ib * 16 + lr;
    #pragma unroll
    for (int ks = 0; ks < 3; ++ks) {
      bf16x8 v;
      #pragma unroll
      for (int e = 0; e < 8; ++e) {
        int c = ks * 32 + h * 8 + e;
        float val;
        if (c < 80)       val = xb[c * T_ + t];
        else if (c == 80) val = 1.0f;
        else              val = 0.0f;
        v[e] = (bf16)val;
      }
      afrag[ib][ks] = v;
    }
  }

  const int nb0 = w * 4;
  #pragma unroll
  for (int mat = 0; mat < 2; ++mat) {
    const float* W    = mat ? Wq : Wk;
    const float* bias = mat ? bq : bk;
    bf16* outp        = mat ? Qb : Kb;

    f32x4 acc[2][4];
    #pragma unroll
    for (int ib = 0; ib < 2; ++ib)
      #pragma unroll
      for (int nb = 0; nb < 4; ++nb)
        acc[ib][nb] = f32x4{0.f, 0.f, 0.f, 0.f};

    #pragma unroll
    for (int nb = 0; nb < 4; ++nb) {
      int d = (nb0 + nb) * 16 + lr;
      #pragma unroll
      for (int ks = 0; ks < 3; ++ks) {
        bf16x8 bv;
        #pragma unroll
        for (int e = 0; e < 8; ++e) {
          int c = ks * 32 + h * 8 + e;
          float val;
          if (c < 80)       val = W[d * C_ + c];
          else if (c == 80) val = bias[d];
          else              val = 0.0f;
          bv[e] = (bf16)val;
        }
        #pragma unroll
        for (int ib = 0; ib < 2; ++ib)
          acc[ib][nb] = MFMA16(afrag[ib][ks], bv, acc[ib][nb]);
      }
    }

    #pragma unroll
    for (int ib = 0; ib < 2; ++ib)
      #pragma unroll
      for (int nb = 0; nb < 4; ++nb) {
        int d = (nb0 + nb) * 16 + lr;
        #pragma unroll
        for (int r = 0; r < 4; ++r) {
          int t = t0 + ib * 16 + h * 4 + r;
          outp[(size_t)(b * T_ + t) * D_ + d] = (bf16)acc[ib][nb][r];
        }
      }
  }
}

// ---------------------------------------------------------------------------
// Kernel 2: flash attention, swapped-QK 32x32 structure.
// Wave owns 32 i-rows: K resident in regs (B-frags), per 32-j tile compute
// S^T = mfma(Q, K) so lane holds 16 j-values for ONE softmax row (i=lane&31):
// in-register softmax (1 cross-half shuffle). P -> bf16 B-frag in-register
// (pack + cross-half exchange). V^T A-frags straight from xbf[c][t] (L2).
// Q tile double-buffered in LDS via global_load_lds with pre-swizzled
// source; ONE barrier per tile (T3 2-phase). Batch->XCD pinning.
// ---------------------------------------------------------------------------
__global__ __launch_bounds__(256, 2) void attn_kernel(
    const bf16* __restrict__ Kb,   // [B][T][D]
    const bf16* __restrict__ Qb,   // [B][T][D]
    const bf16* __restrict__ xbf,  // [B][C][T]
    float* __restrict__ Opart,     // [NS][B][C][T]
    float* __restrict__ mpart,     // [NS][B][T]
    float* __restrict__ lpart)     // [NS][B][T]
{
  constexpr int BN = 32, NT = T_ / BN;   // 64 j-tiles total
  constexpr int JT_PER = NT / NS;        // 16 per split
  __shared__ bf16 qlds[2][BN * D_];      // 2 x 16 KB

  const int flat = blockIdx.x;
  const int b    = flat & 7;             // batch -> XCD
  const int rem  = flat >> 3;
  const int it   = rem & 15;             // 16 i-tiles of 128
  const int s    = rem >> 4;             // split
  const int i0   = it * 128;

  const int tid  = threadIdx.x;
  const int w    = tid >> 6;
  const int lane = tid & 63;
  const int il   = lane & 31;
  const int hi   = lane >> 5;
  const int iw   = i0 + w * 32;          // this wave's 32 i-rows

  const bf16* Kbase = Kb  + (size_t)b * T_ * D_;
  const bf16* Qbase = Qb  + (size_t)b * T_ * D_;
  const bf16* Vbase = xbf + (size_t)b * C_ * T_;

  // K B-frags (resident): kf[ks] = K[iw+il][hi*8 + ks*16 .. +7]
  bf16x8 kf[16];
  {
    const bf16* kp = Kbase + (size_t)(iw + il) * D_ + hi * 8;
    #pragma unroll
    for (int ks = 0; ks < 16; ++ks)
      kf[ks] = *reinterpret_cast<const bf16x8*>(kp + ks * 16);
  }

  f32x16 oacc[3];
  #pragma unroll
  for (int cb = 0; cb < 3; ++cb)
    #pragma unroll
    for (int r = 0; r < 16; ++r) oacc[cb][r] = 0.f;
  float m_run = -INFINITY, l_run = 0.f;

  // Q tile stage: LDS slot (j, c) holds Q[j][c ^ j] (16B chunks) so the
  // fully-XOR-swizzled ds_read_b128 is bank-conflict-free. Linear LDS dest
  // (global_load_lds requirement), swizzle folded into the global source.
  auto stage = [&](int jt, int buf) {
    #pragma unroll
    for (int q = 0; q < 4; ++q) {
      int f = tid + 256 * q;             // 16B-chunk id, 0..1023
      int j = f >> 5, c = f & 31;
      const bf16* src = Qbase + (size_t)(jt * BN + j) * D_ + ((c ^ j) << 3);
      __builtin_amdgcn_global_load_lds((gq_t)src,
          (lq_t)&qlds[buf][(q * 256 + w * 64) * 8], 16, 0, 0);
    }
  };

  const int jt0 = s * JT_PER, jtend = jt0 + JT_PER;

  stage(jt0, 0);
  asm volatile("s_waitcnt vmcnt(0)" ::: "memory");
  __syncthreads();

  int cur = 0;
  for (int jt = jt0; jt < jtend; ++jt, cur ^= 1) {
    if (jt + 1 < jtend) stage(jt + 1, cur ^ 1);   // prefetch -> other buffer

    // V^T A-frags from L2: vf[cb][kj] = xbf[cb*32+il][jt*32 + hi*8 + kj*16]
    // (cb=2 rows 80..95 read in-workspace garbage; their D-rows are never
    //  stored, and MFMA rows are independent.)
    bf16x8 vf[3][2];
    #pragma unroll
    for (int cb = 0; cb < 3; ++cb)
      #pragma unroll
      for (int kj = 0; kj < 2; ++kj)
        vf[cb][kj] = *reinterpret_cast<const bf16x8*>(
            Vbase + (size_t)(cb * 32 + il) * T_ + jt * BN + hi * 8 + kj * 16);

    // --- S^T = Q K^T: lane holds S[j-slice][i = iw + il] ---
    f32x16 sacc;
    #pragma unroll
    for (int r = 0; r < 16; ++r) sacc[r] = 0.f;
    __builtin_amdgcn_s_setprio(1);
    #pragma unroll
    for (int ks = 0; ks < 16; ++ks) {
      bf16x8 qa = *reinterpret_cast<const bf16x8*>(
          &qlds[cur][il * 256 + (((hi + 2 * ks) ^ il) << 3)]);
      sacc = MFMA32(qa, kf[ks], sacc);
    }
    __builtin_amdgcn_s_setprio(0);

    // --- in-register online softmax (row i = lane&31; j = (r&3)+8*(r>>2)+4*hi
    //     plus the partner half-lane's complementary 16 values) ---
    float p16[16];
    #pragma unroll
    for (int r = 0; r < 16; ++r) p16[r] = sacc[r];
    float mx = p16[0];
    #pragma unroll
    for (int r = 1; r < 16; ++r) mx = fmaxf(mx, p16[r]);
    mx = fmaxf(mx, __shfl_xor(mx, 32));

    // defer-max (T13): raw-domain threshold 48 = 3 score units (P <= e^3)
    if (!__all(mx <= m_run + 48.f)) {
      float mnew  = fmaxf(m_run, mx);
      float alpha = __expf((m_run - mnew) * SCALE_INV);
      m_run = mnew;
      l_run *= alpha;
      #pragma unroll
      for (int cb = 0; cb < 3; ++cb)
        #pragma unroll
        for (int r = 0; r < 16; ++r) oacc[cb][r] *= alpha;
    }
    float rs = 0.f;
    #pragma unroll
    for (int r = 0; r < 16; ++r) {
      p16[r] = __expf((p16[r] - m_run) * SCALE_INV);
      rs += p16[r];
    }
    rs += __shfl_xor(rs, 32);
    l_run += rs;

    // --- P -> bf16 B-frags in-register (pack + cross-half exchange) ---
    uint32_t a0 = pkbf(p16[0],  p16[1]),  a1 = pkbf(p16[2],  p16[3]);
    uint32_t c0 = pkbf(p16[4],  p16[5]),  c1 = pkbf(p16[6],  p16[7]);
    uint32_t a2 = pkbf(p16[8],  p16[9]),  a3 = pkbf(p16[10], p16[11]);
    uint32_t c2 = pkbf(p16[12], p16[13]), c3 = pkbf(p16[14], p16[15]);
    uint32_t a0s = __shfl_xor(a0, 32), a1s = __shfl_xor(a1, 32);
    uint32_t c0s = __shfl_xor(c0, 32), c1s = __shfl_xor(c1, 32);
    uint32_t a2s = __shfl_xor(a2, 32), a3s = __shfl_xor(a3, 32);
    uint32_t c2s = __shfl_xor(c2, 32), c3s = __shfl_xor(c3, 32);
    const bool h = (hi != 0);
    u32x4 pb0 = { h ? c0s : a0, h ? c1s : a1, h ? c0 : a0s, h ? c1 : a1s };
    u32x4 pb1 = { h ? c2s : a2, h ? c3s : a3, h ? c2 : a2s, h ? c3 : a3s };
    bf16x8 pbf0 = __builtin_bit_cast(bf16x8, pb0);
    bf16x8 pbf1 = __builtin_bit_cast(bf16x8, pb1);

    // --- PV: oacc[cb] += V^T[cb] . P  (D rows = c, cols = i) ---
    __builtin_amdgcn_s_setprio(1);
    #pragma unroll
    for (int cb = 0; cb < 3; ++cb) {
      oacc[cb] = MFMA32(vf[cb][0], pbf0, oacc[cb]);
      oacc[cb] = MFMA32(vf[cb][1], pbf1, oacc[cb]);
    }
    __builtin_amdgcn_s_setprio(0);

    asm volatile("s_waitcnt vmcnt(0)" ::: "memory");  // next-tile stage done
    __syncthreads();
  }

  // --- epilogue: unnormalized partials ---
  float* ob = Opart + (size_t)(s * B_ + b) * C_ * T_;
  #pragma unroll
  for (int cb = 0; cb < 3; ++cb)
    #pragma unroll
    for (int r = 0; r < 16; ++r) {
      if (cb < 2 || r < 8) {
        int c = cb * 32 + (r & 3) + 8 * (r >> 2) + 4 * hi;
        ob[(size_t)c * T_ + iw + il] = oacc[cb][r];
      }
    }
  if (lane < 32) {
    mpart[(size_t)(s * B_ + b) * T_ + iw + il] = m_run;
    lpart[(size_t)(s * B_ + b) * T_ + iw + il] = l_run;
  }
}

// ---------------------------------------------------------------------------
// Kernel 3: merge splits (unchanged).
// ---------------------------------------------------------------------------
__global__ __launch_bounds__(256) void merge_kernel(
    const float* __restrict__ Opart,  // [NS][B][C][T]
    const float* __restrict__ mpart,  // [NS][B][T]
    const float* __restrict__ lpart,  // [NS][B][T]
    float* __restrict__ out)          // [B][C][T]
{
  const int b    = blockIdx.y;
  const int tid  = threadIdx.x;
  const int w    = tid >> 6;
  const int lane = tid & 63;
  const int t    = blockIdx.x * 64 + lane;

  float m[NS];
  float mmax = -INFINITY;
  #pragma unroll
  for (int s2 = 0; s2 < NS; ++s2) {
    m[s2] = mpart[(size_t)(s2 * B_ + b) * T_ + t];
    mmax = fmaxf(mmax, m[s2]);
  }
  float e[NS];
  float lsum = 0.f;
  #pragma unroll
  for (int s2 = 0; s2 < NS; ++s2) {
    e[s2] = __expf((m[s2] - mmax) * SCALE_INV);
    lsum += e[s2] * lpart[(size_t)(s2 * B_ + b) * T_ + t];
  }
  const float inv = 1.0f / lsum;

  const int c0 = w * 20;
  for (int c = c0; c < c0 + 20; ++c) {
    float acc = 0.f;
    #pragma unroll
    for (int s2 = 0; s2 < NS; ++s2)
      acc += Opart[((size_t)(s2 * B_ + b) * C_ + c) * T_ + t] * e[s2];
    out[((size_t)b * C_ + c) * T_ + t] = acc * inv;
  }
}

// ---------------------------------------------------------------------------
extern "C" void kernel_launch(void* const* d_in, const int* in_sizes, int n_in,
                              void* d_out, int out_size, void* d_ws, size_t ws_size,
                              hipStream_t stream) {
  (void)in_sizes; (void)n_in; (void)out_size; (void)ws_size;
  const float* x  = (const float*)d_in[0];
  const float* Wk = (const float*)d_in[1];
  const float* bk = (const float*)d_in[2];
  const float* Wq = (const float*)d_in[3];
  const float* bq = (const float*)d_in[4];
  float* out = (float*)d_out;

  char* ws = (char*)d_ws;
  const size_t MB = 1024 * 1024;
  bf16*  Kb    = (bf16*)(ws);                 // 8 MB
  bf16*  Qb    = (bf16*)(ws + 8 * MB);        // 8 MB
  bf16*  xbf   = (bf16*)(ws + 16 * MB);       // 2.625 MB
  float* Opart = (float*)(ws + 19 * MB);      // 20.97 MB
  float* mpart = (float*)(ws + 41 * MB);      // 256 KB
  float* lpart = (float*)(ws + 42 * MB);      // 256 KB

  dim3 blk(256);
  dim3 g1(T_ / 32, B_);
  proj_kernel<<<g1, blk, 0, stream>>>(x, Wk, bk, Wq, bq, Kb, Qb, xbf);
  attn_kernel<<<dim3(16 * NS * B_), blk, 0, stream>>>(Kb, Qb, xbf, Opart, mpart, lpart);
  dim3 g3(T_ / 64, B_);
  merge_kernel<<<g3, blk, 0, stream>>>(Opart, mpart, lpart, out);
}